// Round 1
// baseline (135.184 us; speedup 1.0000x reference)
//
#include <hip/hip_runtime.h>
#include <math.h>

#define Bc 32
#define Cc 64
#define Tc 128
#define Vc 25
#define OUTC 64
#define RELC 8
#define TSC 9

typedef __bf16 bf16x8 __attribute__((ext_vector_type(8)));
typedef float f32x4 __attribute__((ext_vector_type(4)));

static __device__ __forceinline__ ushort f2bf(float f) {
    union { float f; uint u; } v; v.f = f;
    uint u = v.u;
    u += 0x7fff + ((u >> 16) & 1);   // RNE
    return (ushort)(u >> 16);
}

// load 8 bf16 (4 dwords) from an LDS row at dword offset dwoff; rows are
// padded to odd dword strides so the 4 b32 phases are ~2-way (free) on banks
static __device__ __forceinline__ bf16x8 ldfrag(const ushort* row, int dwoff) {
    const uint* p = (const uint*)row + dwoff;
    uint4 u;
    u.x = p[0]; u.y = p[1]; u.z = p[2]; u.w = p[3];
    return __builtin_bit_cast(bf16x8, u);
}

// XCD swizzle: dispatch d -> XCD d%8 (round-robin). Map so batch b sits on
// XCD b%8 in ALL kernels: x lines primed by k_mean get re-hit by k_dynconv,
// and zz dirty lines written by k_dynconv get read by k_conv3 from same L2.
// d = (slot<<3)|xcd ; slot = (b>>3)*64 | c  -> bijective over 2048.
static __device__ __forceinline__ void swz_bc(int d, int& b, int& c) {
    int slot = d >> 3;
    b = (d & 7) + 8 * (slot >> 6);
    c = slot & 63;
}

// ---------------- K1: xm[b,c,v] = mean_t x[b,c,t,v] ----------------
__global__ __launch_bounds__(256) void k_mean(const float* __restrict__ x,
                                              float* __restrict__ xm) {
    int b, c;
    swz_bc(blockIdx.x, b, c);
    int bc = b * Cc + c;
    int v  = threadIdx.x & 31;
    int tg = threadIdx.x >> 5;
    const float* xp = x + (size_t)bc * Tc * Vc;
    float s = 0.f;
    if (v < Vc) {
        for (int t = tg; t < Tc; t += 8) s += xp[t * Vc + v];
    }
    __shared__ float red[8][32];
    red[tg][v] = s;
    __syncthreads();
    if (tg == 0 && v < Vc) {
        float tot = 0.f;
#pragma unroll
        for (int g = 0; g < 8; ++g) tot += red[g][v];
        xm[bc * Vc + v] = tot * (1.0f / Tc);
    }
}

// ---------------- K2: dynconv via MFMA over 9 shifted GEMMs -------------------
// rel-network fused in: per block recompute s1[r][j], s2[r][i] from xm (cheap,
// 25K FMA + 5K tanh per block) instead of a separate k_rel kernel + dT buffer.
// z[t,i] = sum_k sum_j xs[t+k, j] * W[j,i,k]; one 16x16x32 K-step per shift k.
// MFMA frags read only dwords 0..15 of each 19-dword row, so only ushorts
// 25..31 (K-pad) and the never-written rows need zeroing — not the full tile.
#define XSROW 38     // 19 dwords: odd-dword row stride -> ~2-way banks
#define XSROWS 136
__global__ __launch_bounds__(256, 4) void k_dynconv(const float* __restrict__ x,
                                                    const float* __restrict__ xm,
                                                    const float* __restrict__ w1,
                                                    const float* __restrict__ b1,
                                                    const float* __restrict__ w2,
                                                    const float* __restrict__ b2,
                                                    const float* __restrict__ w4,
                                                    const float* __restrict__ b4,
                                                    const float* __restrict__ A,
                                                    ushort* __restrict__ z) {
    int b, c;
    swz_bc(blockIdx.x, b, c);
    int bc = b * Cc + c;
    __shared__ ushort xs[XSROWS * XSROW];     // 10.3 KB, padded x in bf16
    __shared__ ushort sB[TSC * 32 * XSROW];   // 21.9 KB, W[j,i,k] as [k][i][j]
    __shared__ float sw4[TSC * RELC];
    __shared__ float sb4[TSC];
    __shared__ float sxm[Cc * Vc];            // 6.4 KB
    __shared__ float sS[2][RELC][Vc];         // 1.6 KB: s1[r][j], s2[r][i]
    // total LDS ~40.5 KB -> still 4 blocks/CU (4*40.5 = 162 KB <= 160 KiB+grain)
    int tid = threadIdx.x;
    uint* sBu = (uint*)sB;
    uint* xsu = (uint*)xs;

    // ---- phase 1a: minimal sB zeroing ----
    // rows i in [25,32) per k (never written by phase 2, read by bb1): dwords 0..15
    for (int idx = tid; idx < 63 * 16; idx += 256) {
        int rr = idx >> 4, dw = idx & 15;
        int k = rr / 7, i = 25 + rr % 7;
        sBu[(k * 32 + i) * 19 + dw] = 0;
    }
    // rows i in [0,25): K-pad ushorts 25..31 only (disjoint bytes from data)
    for (int idx = tid; idx < 225 * 4; idx += 256) {
        int rr = idx >> 2, w = idx & 3;
        int row = (rr / 25) * 32 + (rr % 25);
        if (w == 0) sB[row * XSROW + 25] = 0;
        else        sBu[row * 19 + 12 + w] = 0;
    }
    // ---- phase 1b: xs zero pad ----
    // causal-pad rows 0..7: dwords 0..15
    for (int idx = tid; idx < 8 * 16; idx += 256) {
        int r = idx >> 4, dw = idx & 15;
        xsu[r * 19 + dw] = 0;
    }
    // data rows 8..135: K-pad ushorts 25..31
    for (int idx = tid; idx < 128 * 4; idx += 256) {
        int r = 8 + (idx >> 2), w = idx & 3;
        if (w == 0) xs[r * XSROW + 25] = 0;
        else        xsu[r * 19 + 12 + w] = 0;
    }
    // ---- phase 1c: stage x via linear float4 reads (800 loads vs 5168 scalar)
    const float4* xp4 = (const float4*)(x + (size_t)bc * Tc * Vc);
    for (int idx = tid; idx < 800; idx += 256) {
        float4 f = xp4[idx];
        int f0 = idx * 4;
        float fe[4] = {f.x, f.y, f.z, f.w};
#pragma unroll
        for (int e = 0; e < 4; ++e) {
            int ff = f0 + e;
            int t = ff / 25, cl = ff - t * 25;
            xs[(t + 8) * XSROW + cl] = f2bf(fe[e]);
        }
    }
    // ---- phase 1d: stage xm for this batch + per-c conv4 weights ----
    for (int idx = tid; idx < Cc * Vc; idx += 256)
        sxm[idx] = xm[(size_t)b * Cc * Vc + idx];
    if (tid < TSC * RELC) sw4[tid] = w4[(c * TSC + tid / RELC) * RELC + tid % RELC];
    if (tid < TSC) sb4[tid] = b4[c * TSC + tid];
    __syncthreads();

    // ---- phase 1e: rel-net linear layers: sS[0][r][j]=x1, sS[1][r][i]=x2 ----
    for (int idx = tid; idx < 2 * RELC * Vc; idx += 256) {
        int half = idx / (RELC * Vc);
        int rem = idx - half * (RELC * Vc);
        int r = rem / Vc, v = rem - (rem / Vc) * Vc;
        const float* w = half ? w2 : w1;
        float acc = (half ? b2 : b1)[r];
#pragma unroll 8
        for (int cc = 0; cc < Cc; ++cc) acc += w[r * Cc + cc] * sxm[cc * Vc + v];
        sS[half][r][v] = acc;
    }
    __syncthreads();

    // phase 2: build sB[k][i][j] = b4 + A[j,i] + sum_r w4[k,r]*tanh(s1[r][j]-s2[r][i])
    for (int p = tid; p < Vc * Vc; p += 256) {
        int j = p / Vc, i = p - (p / Vc) * Vc;
        float dv[RELC];
#pragma unroll
        for (int r = 0; r < RELC; ++r) dv[r] = tanhf(sS[0][r][j] - sS[1][r][i]);
        float av = A[p];
#pragma unroll
        for (int k = 0; k < TSC; ++k) {
            float acc = sb4[k] + av;
#pragma unroll
            for (int r = 0; r < RELC; ++r) acc += sw4[k * RELC + r] * dv[r];
            sB[(k * 32 + i) * XSROW + j] = f2bf(acc);
        }
    }
    __syncthreads();

    // phase 3: MFMA. wave w owns m-tiles {2w,2w+1}; both n-tiles.
    int wv = tid >> 6, lane = tid & 63, lr = lane & 15, q = lane >> 4;
    f32x4 acc[2][2];
#pragma unroll
    for (int mi = 0; mi < 2; ++mi)
#pragma unroll
        for (int ni = 0; ni < 2; ++ni) acc[mi][ni] = (f32x4)0.0f;

#pragma unroll
    for (int k = 0; k < TSC; ++k) {
        int r0 = (wv * 2) * 16 + lr + k;
        bf16x8 a0 = ldfrag(xs + r0 * XSROW, q * 4);
        bf16x8 a1 = ldfrag(xs + (r0 + 16) * XSROW, q * 4);
        bf16x8 bb0 = ldfrag(sB + (k * 32 + lr) * XSROW, q * 4);
        bf16x8 bb1 = ldfrag(sB + (k * 32 + 16 + lr) * XSROW, q * 4);
        acc[0][0] = __builtin_amdgcn_mfma_f32_16x16x32_bf16(a0, bb0, acc[0][0], 0, 0, 0);
        acc[0][1] = __builtin_amdgcn_mfma_f32_16x16x32_bf16(a0, bb1, acc[0][1], 0, 0, 0);
        acc[1][0] = __builtin_amdgcn_mfma_f32_16x16x32_bf16(a1, bb0, acc[1][0], 0, 0, 0);
        acc[1][1] = __builtin_amdgcn_mfma_f32_16x16x32_bf16(a1, bb1, acc[1][1], 0, 0, 0);
    }

    // epilogue: D row = q*4+reg (t), col = lr (i); store z bf16 [bc][t][i]
    ushort* zp = z + (size_t)bc * Tc * Vc;
#pragma unroll
    for (int mi = 0; mi < 2; ++mi) {
        int t0 = (wv * 2 + mi) * 16 + q * 4;
#pragma unroll
        for (int ni = 0; ni < 2; ++ni) {
            int i = ni * 16 + lr;
            if (i < Vc) {
#pragma unroll
                for (int r = 0; r < 4; ++r)
                    zp[(t0 + r) * Vc + i] = f2bf(acc[mi][ni][r]);
            }
        }
    }
}

// ---------------- K3: conv3 via MFMA: out[col,o] = sum_c z[col,c]*w3[o,c] -----
// transpose staging packs 2 c's per ds_write_b32; lane map gives 16 cp x 4 colg
// per wave -> bank residues uniformly 2-way (free per m136)
// 1-D grid of 800 with b -> XCD b%8 so zz[b] reads hit the L2 that holds the
// dirty lines k_dynconv just wrote (1.6 MB/XCD < 4 MB).
#define SZROW 70     // 35 dwords: odd-dword stride
#define COLT 128
__global__ __launch_bounds__(256, 5) void k_conv3(const ushort* __restrict__ z,
                                                  const float* __restrict__ w3,
                                                  const float* __restrict__ b3,
                                                  float* __restrict__ out) {
    int d = blockIdx.x;
    int slot = d >> 3;                  // 0..99
    int b = (d & 7) + 8 * (slot / 25);  // b%8 == d%8
    int cx = slot % 25;
    int col0 = cx * COLT;
    __shared__ ushort sz[COLT * SZROW];    // 17.9 KB, z-tile transposed [col][c]
    __shared__ ushort sw3[OUTC * SZROW];   // 9.0 KB, w3 bf16 [o][c]
    int tid = threadIdx.x;

    for (int idx = tid; idx < OUTC * Cc; idx += 256)
        sw3[(idx >> 6) * SZROW + (idx & 63)] = f2bf(w3[idx]);

    const ushort* zb = z + (size_t)b * Cc * Tc * Vc;
    uint* szd = (uint*)sz;
#pragma unroll
    for (int s = 0; s < 2; ++s) {
        int task = tid + 256 * s;            // 512 tasks: 32 c-pairs x 16 col-groups
        int cp = (task & 15) + 16 * s;       // c-pair 0..31
        int colg = (task >> 4) & 15;         // col-group 0..15
        int c0 = cp * 2, col = colg * 8;
        uint4 u0 = *(const uint4*)(zb + (size_t)(c0 + 0) * Tc * Vc + col0 + col);
        uint4 u1 = *(const uint4*)(zb + (size_t)(c0 + 1) * Tc * Vc + col0 + col);
        uint a0[4] = {u0.x, u0.y, u0.z, u0.w};
        uint a1[4] = {u1.x, u1.y, u1.z, u1.w};
#pragma unroll
        for (int e = 0; e < 8; ++e) {
            uint v0 = (a0[e >> 1] >> ((e & 1) * 16)) & 0xffffu;
            uint v1 = (a1[e >> 1] >> ((e & 1) * 16)) & 0xffffu;
            szd[(col + e) * (SZROW / 2) + cp] = v0 | (v1 << 16);
        }
    }
    __syncthreads();

    int wv = tid >> 6, lane = tid & 63, lr = lane & 15, q = lane >> 4;
    f32x4 acc[2][4];
#pragma unroll
    for (int mi = 0; mi < 2; ++mi)
#pragma unroll
        for (int ni = 0; ni < 4; ++ni) acc[mi][ni] = (f32x4)0.0f;

#pragma unroll
    for (int ks = 0; ks < 2; ++ks) {
        bf16x8 a[2], bb[4];
#pragma unroll
        for (int mi = 0; mi < 2; ++mi)
            a[mi] = ldfrag(sz + ((wv * 2 + mi) * 16 + lr) * SZROW, ks * 16 + q * 4);
#pragma unroll
        for (int ni = 0; ni < 4; ++ni)
            bb[ni] = ldfrag(sw3 + (ni * 16 + lr) * SZROW, ks * 16 + q * 4);
#pragma unroll
        for (int mi = 0; mi < 2; ++mi)
#pragma unroll
            for (int ni = 0; ni < 4; ++ni)
                acc[mi][ni] = __builtin_amdgcn_mfma_f32_16x16x32_bf16(a[mi], bb[ni], acc[mi][ni], 0, 0, 0);
    }

    // store: lane holds out[col = col0+mt*16+q*4+reg][o = ni*16+lr], float4 along col
#pragma unroll
    for (int ni = 0; ni < 4; ++ni) {
        int o = ni * 16 + lr;
        float bias = b3[o];
        float* ob = out + ((size_t)b * OUTC + o) * Tc * Vc;
#pragma unroll
        for (int mi = 0; mi < 2; ++mi) {
            int cb = col0 + (wv * 2 + mi) * 16 + q * 4;
            float4 st = {acc[mi][ni][0] + bias, acc[mi][ni][1] + bias,
                         acc[mi][ni][2] + bias, acc[mi][ni][3] + bias};
            *(float4*)(ob + cb) = st;
        }
    }
}

extern "C" void kernel_launch(void* const* d_in, const int* in_sizes, int n_in,
                              void* d_out, int out_size, void* d_ws, size_t ws_size,
                              hipStream_t stream) {
    const float* x  = (const float*)d_in[0];
    const float* A  = (const float*)d_in[1];
    const float* w1 = (const float*)d_in[2];
    const float* b1 = (const float*)d_in[3];
    const float* w2 = (const float*)d_in[4];
    const float* b2 = (const float*)d_in[5];
    const float* w3 = (const float*)d_in[6];
    const float* b3 = (const float*)d_in[7];
    const float* w4 = (const float*)d_in[8];
    const float* b4 = (const float*)d_in[9];
    float* out = (float*)d_out;

    float* ws = (float*)d_ws;
    float* xm = ws;                                  // 51200 floats
    ushort* zz = (ushort*)(ws + 51200);              // B*C*T*V bf16 (13.1 MB)

    k_mean<<<Bc * Cc, 256, 0, stream>>>(x, xm);
    k_dynconv<<<Bc * Cc, 256, 0, stream>>>(x, xm, w1, b1, w2, b2, w4, b4, A, zz);
    k_conv3<<<(Tc * Vc) / COLT * Bc, 256, 0, stream>>>(zz, w3, b3, out);
}

// Round 3
// 128.500 us; speedup vs baseline: 1.0520x; 1.0520x over previous
//
#include <hip/hip_runtime.h>
#include <math.h>

#define Bc 32
#define Cc 64
#define Tc 128
#define Vc 25
#define OUTC 64
#define RELC 8
#define TSC 9

typedef __bf16 bf16x8 __attribute__((ext_vector_type(8)));
typedef float f32x4 __attribute__((ext_vector_type(4)));

static __device__ __forceinline__ ushort f2bf(float f) {
    union { float f; uint u; } v; v.f = f;
    uint u = v.u;
    u += 0x7fff + ((u >> 16) & 1);   // RNE
    return (ushort)(u >> 16);
}

static __device__ __forceinline__ float bf2f(uint bits) {
    union { uint u; float f; } v; v.u = bits << 16;
    return v.f;
}

// load 8 bf16 (4 dwords) from an LDS row at dword offset dwoff; rows are
// padded to odd dword strides so the 4 b32 phases are ~2-way (free) on banks
static __device__ __forceinline__ bf16x8 ldfrag(const ushort* row, int dwoff) {
    const uint* p = (const uint*)row + dwoff;
    uint4 u;
    u.x = p[0]; u.y = p[1]; u.z = p[2]; u.w = p[3];
    return __builtin_bit_cast(bf16x8, u);
}

// XCD swizzle: dispatch d -> XCD d%8 (round-robin). Keep batch b on XCD b%8 in
// prep/dynconv/conv3 so xpad lines written by k_prep and zz lines written by
// k_dynconv are re-read from the same per-XCD L2.
static __device__ __forceinline__ void swz_bc(int d, int& b, int& c) {
    int slot = d >> 3;
    b = (d & 7) + 8 * (slot >> 6);
    c = slot & 63;
}

#define XSROW 38     // 19 dwords: odd-dword row stride -> ~2-way banks
#define XSROWS 136
#define XTILE (XSROWS * XSROW)   // 5168 ushorts = 10336 B = 646 uint4

// ---------------- K1: xm = mean_t x  AND  xpad = padded bf16 tile ------------
// xpad[bc] byte-layout == dynconv's xs LDS tile (causal-pad rows 0..7 zero,
// data at row t+8, K-pad ushorts 25..31 zero, 32..37 zeroed for determinism).
__global__ __launch_bounds__(256) void k_prep(const float* __restrict__ x,
                                              float* __restrict__ xm,
                                              ushort* __restrict__ xpad) {
    int b, c;
    swz_bc(blockIdx.x, b, c);
    int bc = b * Cc + c;
    __shared__ ushort sxp[XTILE];      // 10.3 KB
    __shared__ float red[8][32];
    int tid = threadIdx.x;
    uint* sxpu = (uint*)sxp;

    // causal-pad rows 0..7 = dwords [0,152): zero fully
    for (int idx = tid; idx < 152; idx += 256) sxpu[idx] = 0;
    // data rows 8..135: zero ushort 25 and dwords 13..18 (K-pad + tail)
    for (int idx = tid; idx < 128 * 7; idx += 256) {
        int r = 8 + idx / 7, w = idx - (idx / 7) * 7;
        if (w == 0) sxp[r * XSROW + 25] = 0;
        else        sxpu[r * 19 + 12 + w] = 0;
    }
    // convert + scatter: 800 linear float4 reads
    const float4* xp4 = (const float4*)(x + (size_t)bc * Tc * Vc);
    for (int idx = tid; idx < 800; idx += 256) {
        float4 f = xp4[idx];
        int f0 = idx * 4;
        float fe[4] = {f.x, f.y, f.z, f.w};
#pragma unroll
        for (int e = 0; e < 4; ++e) {
            int ff = f0 + e;
            int t = ff / 25, cl = ff - t * 25;
            sxp[(t + 8) * XSROW + cl] = f2bf(fe[e]);
        }
    }
    // mean over t — identical pattern/order to the original k_mean (exact
    // numerics); re-read is L1/L2-warm from the float4 pass above
    int v = tid & 31, tg = tid >> 5;
    const float* xp = x + (size_t)bc * Tc * Vc;
    float s = 0.f;
    if (v < Vc) {
        for (int t = tg; t < Tc; t += 8) s += xp[t * Vc + v];
    }
    red[tg][v] = s;
    __syncthreads();
    if (tg == 0 && v < Vc) {
        float tot = 0.f;
#pragma unroll
        for (int g = 0; g < 8; ++g) tot += red[g][v];
        xm[bc * Vc + v] = tot * (1.0f / Tc);
    }
    // linear copy-out (coalesced 16B/lane); barrier above covers sxp writes
    uint4* xo = (uint4*)(xpad + (size_t)bc * XTILE);
    const uint4* si = (const uint4*)sxp;
    for (int idx = tid; idx < 646; idx += 256) xo[idx] = si[idx];
}

// ---------------- K2: dT[b, j*25+i, r] = bf16(tanh(x1[b,r,j] - x2[b,r,i])) ----
__global__ __launch_bounds__(256) void k_rel(const float* __restrict__ xm,
                                             const float* __restrict__ w1,
                                             const float* __restrict__ b1,
                                             const float* __restrict__ w2,
                                             const float* __restrict__ b2,
                                             ushort* __restrict__ dT) {
    int b = blockIdx.x >> 3, r = blockIdx.x & 7;
    __shared__ float sxm[Cc * Vc];
    __shared__ float s1[Vc], s2[Vc];
    int tid = threadIdx.x;
    for (int idx = tid; idx < Cc * Vc; idx += 256)
        sxm[idx] = xm[(size_t)b * Cc * Vc + idx];
    __syncthreads();
    if (tid < 2 * Vc) {
        int which = tid / Vc, v = tid % Vc;
        const float* w = which ? w2 : w1;
        float acc = which ? b2[r] : b1[r];
        for (int c = 0; c < Cc; ++c) acc += w[r * Cc + c] * sxm[c * Vc + v];
        (which ? s2 : s1)[v] = acc;
    }
    __syncthreads();
    ushort* dp = dT + (size_t)b * Vc * Vc * RELC + r;
    for (int p = tid; p < Vc * Vc; p += 256) {
        int j = p / Vc, i = p % Vc;
        dp[p * RELC] = f2bf(tanhf(s1[j] - s2[i]));
    }
}

// ---------------- K3: dynconv via MFMA over 9 shifted GEMMs -------------------
// z[t,i] = sum_k sum_j xs[t+k, j] * W[j,i,k]; one 16x16x32 K-step per shift k.
// xs staging is now a pure linear copy from xpad (pads pre-baked by k_prep);
// the 3 global loads are issued FIRST so their latency hides under sB zeroing.
__global__ __launch_bounds__(256, 4) void k_dynconv(const ushort* __restrict__ xpad,
                                                    const ushort* __restrict__ dT,
                                                    const float* __restrict__ w4,
                                                    const float* __restrict__ b4,
                                                    const float* __restrict__ A,
                                                    ushort* __restrict__ z) {
    int b, c;
    swz_bc(blockIdx.x, b, c);
    int bc = b * Cc + c;
    __shared__ ushort xs[XTILE];              // 10.3 KB, padded x in bf16
    __shared__ ushort sB[TSC * 32 * XSROW];   // 21.9 KB, W[j,i,k] as [k][i][j]
    __shared__ float sw4[TSC * RELC];
    __shared__ float sb4[TSC];
    // total LDS ~32.5 KB -> 4 blocks/CU at __launch_bounds__(256,4)
    int tid = threadIdx.x;
    uint* sBu = (uint*)sB;

    // ---- stage-issue: 646 uint4 = 2 full rounds + tail(134), static regs ----
    const uint4* xi = (const uint4*)(xpad + (size_t)bc * XTILE);
    uint4 s0 = xi[tid];
    uint4 s1 = xi[tid + 256];
    uint4 s2;
    bool has2 = tid < 134;
    if (has2) s2 = xi[tid + 512];

    // ---- sB zeroing (overlaps the loads above) ----
    // rows i in [25,32) per k (never written by phase 2, read by bb1): dwords 0..15
    for (int idx = tid; idx < 63 * 16; idx += 256) {
        int rr = idx >> 4, dw = idx & 15;
        int k = rr / 7, i = 25 + rr % 7;
        sBu[(k * 32 + i) * 19 + dw] = 0;
    }
    // rows i in [0,25): K-pad ushorts 25..31 only (disjoint bytes from data)
    for (int idx = tid; idx < 225 * 4; idx += 256) {
        int rr = idx >> 2, w = idx & 3;
        int row = (rr / 25) * 32 + (rr % 25);
        if (w == 0) sB[row * XSROW + 25] = 0;
        else        sBu[row * 19 + 12 + w] = 0;
    }
    if (tid < TSC * RELC) sw4[tid] = w4[(c * TSC + tid / RELC) * RELC + tid % RELC];
    if (tid < TSC) sb4[tid] = b4[c * TSC + tid];

    // ---- stage-write: linear LDS writes of the staged registers ----
    uint4* xso = (uint4*)xs;
    xso[tid] = s0;
    xso[tid + 256] = s1;
    if (has2) xso[tid + 512] = s2;
    __syncthreads();

    // phase 2: build sB[k][i][j] = b4 + A[j,i] + sum_r w4[k,r]*d[r,j,i]
    const ushort* dp = dT + (size_t)b * Vc * Vc * RELC;
    for (int p = tid; p < Vc * Vc; p += 256) {
        int j = p / Vc, i = p % Vc;
        uint4 u = *(const uint4*)(dp + p * RELC);
        uint ua[4] = {u.x, u.y, u.z, u.w};
        float dv[RELC];
#pragma unroll
        for (int e = 0; e < RELC; ++e)
            dv[e] = bf2f((ua[e >> 1] >> ((e & 1) * 16)) & 0xffffu);
        float av = A[p];
#pragma unroll
        for (int k = 0; k < TSC; ++k) {
            float acc = sb4[k] + av;
#pragma unroll
            for (int r = 0; r < RELC; ++r) acc += sw4[k * RELC + r] * dv[r];
            sB[(k * 32 + i) * XSROW + j] = f2bf(acc);
        }
    }
    __syncthreads();

    // phase 3: MFMA. wave w owns m-tiles {2w,2w+1}; both n-tiles.
    int wv = tid >> 6, lane = tid & 63, lr = lane & 15, q = lane >> 4;
    f32x4 acc[2][2];
#pragma unroll
    for (int mi = 0; mi < 2; ++mi)
#pragma unroll
        for (int ni = 0; ni < 2; ++ni) acc[mi][ni] = (f32x4)0.0f;

#pragma unroll
    for (int k = 0; k < TSC; ++k) {
        int r0 = (wv * 2) * 16 + lr + k;
        bf16x8 a0 = ldfrag(xs + r0 * XSROW, q * 4);
        bf16x8 a1 = ldfrag(xs + (r0 + 16) * XSROW, q * 4);
        bf16x8 bb0 = ldfrag(sB + (k * 32 + lr) * XSROW, q * 4);
        bf16x8 bb1 = ldfrag(sB + (k * 32 + 16 + lr) * XSROW, q * 4);
        acc[0][0] = __builtin_amdgcn_mfma_f32_16x16x32_bf16(a0, bb0, acc[0][0], 0, 0, 0);
        acc[0][1] = __builtin_amdgcn_mfma_f32_16x16x32_bf16(a0, bb1, acc[0][1], 0, 0, 0);
        acc[1][0] = __builtin_amdgcn_mfma_f32_16x16x32_bf16(a1, bb0, acc[1][0], 0, 0, 0);
        acc[1][1] = __builtin_amdgcn_mfma_f32_16x16x32_bf16(a1, bb1, acc[1][1], 0, 0, 0);
    }

    // epilogue: D row = q*4+reg (t), col = lr (i); store z bf16 [bc][t][i]
    ushort* zp = z + (size_t)bc * Tc * Vc;
#pragma unroll
    for (int mi = 0; mi < 2; ++mi) {
        int t0 = (wv * 2 + mi) * 16 + q * 4;
#pragma unroll
        for (int ni = 0; ni < 2; ++ni) {
            int i = ni * 16 + lr;
            if (i < Vc) {
#pragma unroll
                for (int r = 0; r < 4; ++r)
                    zp[(t0 + r) * Vc + i] = f2bf(acc[mi][ni][r]);
            }
        }
    }
}

// ---------------- K4: conv3 via MFMA: out[col,o] = sum_c z[col,c]*w3[o,c] -----
// transpose staging packs 2 c's per ds_write_b32; lane map gives 16 cp x 4 colg
// per wave -> bank residues uniformly 2-way (free per m136)
// b -> XCD b%8 so zz[b] reads hit the L2 holding dynconv's dirty lines.
#define SZROW 70     // 35 dwords: odd-dword stride
#define COLT 128
__global__ __launch_bounds__(256, 5) void k_conv3(const ushort* __restrict__ z,
                                                  const float* __restrict__ w3,
                                                  const float* __restrict__ b3,
                                                  float* __restrict__ out) {
    int d = blockIdx.x;
    int slot = d >> 3;                  // 0..99
    int b = (d & 7) + 8 * (slot / 25);  // b%8 == d%8
    int cx = slot % 25;
    int col0 = cx * COLT;
    __shared__ ushort sz[COLT * SZROW];    // 17.9 KB, z-tile transposed [col][c]
    __shared__ ushort sw3[OUTC * SZROW];   // 9.0 KB, w3 bf16 [o][c]
    int tid = threadIdx.x;

    for (int idx = tid; idx < OUTC * Cc; idx += 256)
        sw3[(idx >> 6) * SZROW + (idx & 63)] = f2bf(w3[idx]);

    const ushort* zb = z + (size_t)b * Cc * Tc * Vc;
    uint* szd = (uint*)sz;
#pragma unroll
    for (int s = 0; s < 2; ++s) {
        int task = tid + 256 * s;            // 512 tasks: 32 c-pairs x 16 col-groups
        int cp = (task & 15) + 16 * s;       // c-pair 0..31
        int colg = (task >> 4) & 15;         // col-group 0..15
        int c0 = cp * 2, col = colg * 8;
        uint4 u0 = *(const uint4*)(zb + (size_t)(c0 + 0) * Tc * Vc + col0 + col);
        uint4 u1 = *(const uint4*)(zb + (size_t)(c0 + 1) * Tc * Vc + col0 + col);
        uint a0[4] = {u0.x, u0.y, u0.z, u0.w};
        uint a1[4] = {u1.x, u1.y, u1.z, u1.w};
#pragma unroll
        for (int e = 0; e < 8; ++e) {
            uint v0 = (a0[e >> 1] >> ((e & 1) * 16)) & 0xffffu;
            uint v1 = (a1[e >> 1] >> ((e & 1) * 16)) & 0xffffu;
            szd[(col + e) * (SZROW / 2) + cp] = v0 | (v1 << 16);
        }
    }
    __syncthreads();

    int wv = tid >> 6, lane = tid & 63, lr = lane & 15, q = lane >> 4;
    f32x4 acc[2][4];
#pragma unroll
    for (int mi = 0; mi < 2; ++mi)
#pragma unroll
        for (int ni = 0; ni < 4; ++ni) acc[mi][ni] = (f32x4)0.0f;

#pragma unroll
    for (int ks = 0; ks < 2; ++ks) {
        bf16x8 a[2], bb[4];
#pragma unroll
        for (int mi = 0; mi < 2; ++mi)
            a[mi] = ldfrag(sz + ((wv * 2 + mi) * 16 + lr) * SZROW, ks * 16 + q * 4);
#pragma unroll
        for (int ni = 0; ni < 4; ++ni)
            bb[ni] = ldfrag(sw3 + (ni * 16 + lr) * SZROW, ks * 16 + q * 4);
#pragma unroll
        for (int mi = 0; mi < 2; ++mi)
#pragma unroll
            for (int ni = 0; ni < 4; ++ni)
                acc[mi][ni] = __builtin_amdgcn_mfma_f32_16x16x32_bf16(a[mi], bb[ni], acc[mi][ni], 0, 0, 0);
    }

    // store: lane holds out[col = col0+mt*16+q*4+reg][o = ni*16+lr], float4 along col
#pragma unroll
    for (int ni = 0; ni < 4; ++ni) {
        int o = ni * 16 + lr;
        float bias = b3[o];
        float* ob = out + ((size_t)b * OUTC + o) * Tc * Vc;
#pragma unroll
        for (int mi = 0; mi < 2; ++mi) {
            int cb = col0 + (wv * 2 + mi) * 16 + q * 4;
            float4 st = {acc[mi][ni][0] + bias, acc[mi][ni][1] + bias,
                         acc[mi][ni][2] + bias, acc[mi][ni][3] + bias};
            *(float4*)(ob + cb) = st;
        }
    }
}

extern "C" void kernel_launch(void* const* d_in, const int* in_sizes, int n_in,
                              void* d_out, int out_size, void* d_ws, size_t ws_size,
                              hipStream_t stream) {
    const float* x  = (const float*)d_in[0];
    const float* A  = (const float*)d_in[1];
    const float* w1 = (const float*)d_in[2];
    const float* b1 = (const float*)d_in[3];
    const float* w2 = (const float*)d_in[4];
    const float* b2 = (const float*)d_in[5];
    const float* w3 = (const float*)d_in[6];
    const float* b3 = (const float*)d_in[7];
    const float* w4 = (const float*)d_in[8];
    const float* b4 = (const float*)d_in[9];
    float* out = (float*)d_out;

    float* ws = (float*)d_ws;
    float* xm = ws;                                   // 51200 floats (204.8 KB)
    ushort* dT = (ushort*)(ws + 51200);               // 160000 ushorts = 80000 floats
    ushort* xpad = (ushort*)(ws + 51200 + 80000);     // 2048*5168 ushorts = 5292032 floats (21.2 MB)
    ushort* zz = (ushort*)(ws + 51200 + 80000 + 5292032);  // B*C*T*V bf16 (13.1 MB)

    k_prep<<<Bc * Cc, 256, 0, stream>>>(x, xm, xpad);
    k_rel<<<Bc * RELC, 256, 0, stream>>>(xm, w1, b1, w2, b2, dT);
    k_dynconv<<<Bc * Cc, 256, 0, stream>>>(xpad, dT, w4, b4, A, zz);
    k_conv3<<<(Tc * Vc) / COLT * Bc, 256, 0, stream>>>(zz, w3, b3, out);
}